// Round 1
// 1854.471 us; speedup vs baseline: 1.1757x; 1.1757x over previous
//
#include <hip/hip_runtime.h>
#include <math.h>
#include <stdint.h>

#define BATCH 4096
#define MCAND 50
#define NTOP 32
#define HID 100

__device__ __forceinline__ uint32_t rotl32(uint32_t v, int d){ return (v<<d)|(v>>(32-d)); }

// JAX threefry2x32 core (20 rounds, 5 key injections)
__device__ __forceinline__ void tf2x32(uint32_t k0, uint32_t k1, uint32_t x0, uint32_t x1,
                                       uint32_t &o0, uint32_t &o1){
  uint32_t k2 = k0 ^ k1 ^ 0x1BD11BDAu;
  x0 += k0; x1 += k1;
#define RND(r) { x0 += x1; x1 = rotl32(x1,(r)); x1 ^= x0; }
  RND(13) RND(15) RND(26) RND(6)
  x0 += k1; x1 += k2 + 1u;
  RND(17) RND(29) RND(16) RND(24)
  x0 += k2; x1 += k0 + 2u;
  RND(13) RND(15) RND(26) RND(6)
  x0 += k0; x1 += k1 + 3u;
  RND(17) RND(29) RND(16) RND(24)
  x0 += k1; x1 += k2 + 4u;
  RND(13) RND(15) RND(26) RND(6)
  x0 += k2; x1 += k0 + 5u;
#undef RND
  o0 = x0; o1 = x1;
}

// XLA ErfInv32 (Giles). w = -log1p(-x*x)
__device__ __forceinline__ float erfinv32(float x){
  float w = -log1pf(-x*x);
  float p;
  if (w < 5.0f){
    w = w - 2.5f;
    p = 2.81022636e-08f;
    p = fmaf(p, w, 3.43273939e-07f);
    p = fmaf(p, w, -3.5233877e-06f);
    p = fmaf(p, w, -4.39150654e-06f);
    p = fmaf(p, w, 0.00021858087f);
    p = fmaf(p, w, -0.00125372503f);
    p = fmaf(p, w, -0.00417768164f);
    p = fmaf(p, w, 0.246640727f);
    p = fmaf(p, w, 1.50140941f);
  } else {
    w = sqrtf(w) - 3.0f;
    p = -0.000200214257f;
    p = fmaf(p, w, 0.000100950558f);
    p = fmaf(p, w, 0.00134934322f);
    p = fmaf(p, w, -0.00367342844f);
    p = fmaf(p, w, 0.00573950773f);
    p = fmaf(p, w, -0.0076224613f);
    p = fmaf(p, w, 0.00943887047f);
    p = fmaf(p, w, 1.00167406f);
    p = fmaf(p, w, 2.83297682f);
  }
  return p*x;
}

// DPP lane swaps (quad_perm): xor1 = 0xB1, xor2 = 0x4E. VALU-only (no DS pipe).
#define DPPPERM(v, CTRL) __int_as_float(__builtin_amdgcn_update_dpp( \
    0, __float_as_int(v), (CTRL), 0xF, 0xF, true))
#define DPPADD(v, CTRL) ((v) + DPPPERM((v), (CTRL)))

// ---------------------------------------------------------------------------
// Piecewise-linear CEM kernel.
//
// h1[c][k] = relu(u_k + a_c*v_k)  with u,v fixed per block  =>  layer-2
// pre-activation is piecewise-linear in the scalar a with fixed breakpoints
// t_k = -u_k/v_k.  Per block we build prefix tables over sorted thresholds:
//   T1[r][n] = b2[n] + sum_{active at rank r} u_k*W2[k][n]
//   T2[r][n] =         sum_{active at rank r} v_k*W2[k][n]
// and per candidate:  h2pre[n] = T1[r_c][n] + a_c*T2[r_c][n],
//                     r_c = #{k : t_k < a_c}.
// q_c = sum_n relu(h2pre[n]) * W3[n] (+b3 at stats).  Exact fp32 math —
// replaces the 3-plane bf16 MFMA GEMM (5.5x-padded FLOPs) entirely.
//
// LDS budget: T(80,800B) + st(400) + eps(200) + sA(200) = 81,600 -> 81,920
// rounded = exactly half the 160KiB pool => 2 blocks/CU.
// ---------------------------------------------------------------------------

__global__ __launch_bounds__(512, 4) void cem_kernel(
    const float* __restrict__ states, const float* __restrict__ W1,
    const float* __restrict__ b1,     const float* __restrict__ W2,
    const float* __restrict__ b2,     const float* __restrict__ W3,
    const float* __restrict__ b3,     float* __restrict__ out)
{
  __shared__ __align__(16) float smem[20400];           // 81,600 B
  float2* const T2D  = (float2*)smem;                   // [101][100] (T1,T2)
  float*  const ST   = smem + 20200;                    // sorted thresholds [100]
  float*  const SEPS = smem + 20300;                    // eps for next iter [50]
  float*  const SA   = smem + 20350;                    // a (then q) per cand [50]
  // init-only scratch inside T region (dead before table rows are written):
  // u: smem[0..99], v: smem[100..199], t: smem[200..299], ord: ints at [300..399]
  int* const ORD = (int*)(smem + 300);

  const int tid  = threadIdx.x;
  const int b    = blockIdx.x;
  const int wv   = tid >> 6;
  const int lane = tid & 63;
  const int gc   = tid >> 3;            // gather candidate (8 lanes/cand)
  const int gj   = tid & 7;
  const bool gact = (tid < 8*MCAND);    // tid < 400

  const float MINV  = -0x1.fffffep-1f;  // nextafter(-1,0)
  const float SQRT2 = 0x1.6a09e6p+0f;   // fp32 sqrt(2)

  // per-thread W3 slice for the gather (n = gj + 8i)
  float w3r[13];
  if (gact){
#pragma unroll
    for (int i = 0; i < 13; ++i){
      int n = gj + (i<<3);
      w3r[i] = (n < HID) ? W3[n] : 0.0f;
    }
  }
  const float sB3v = b3[0];

  // ---------- init P0: u, v, thresholds ----------
  if (tid < HID){
    float u = fmaf(states[2*b], W1[tid], fmaf(states[2*b+1], W1[HID+tid], b1[tid]));
    float v = W1[2*HID+tid];
    float tt = (v != 0.0f) ? (-u / v) : INFINITY;
    smem[tid]     = u;
    smem[HID+tid] = v;
    smem[200+tid] = tt;
  }
  __syncthreads();

  // ---------- init P1: stable rank-by-count, scatter sorted ----------
  if (tid < HID){
    float tk = smem[200+tid];
    int rk = 0;
    for (int j2 = 0; j2 < HID; ++j2){
      float tj = smem[200+j2];
      rk += (tj < tk || (tj == tk && j2 < tid)) ? 1 : 0;
    }
    float u = smem[tid], v = smem[HID+tid];
    // neg-type: active iff a < t (v<0, or v==0 with u>0 -> always active, t=+inf)
    int neg = (v < 0.0f || (v == 0.0f && u > 0.0f)) ? 1 : 0;
    ST[rk]  = tk;
    ORD[rk] = tid | (neg << 7);
  }
  __syncthreads();

  // ---------- init P2: wave0 builds prefix tables; wave7 does RNG setup ----------
  uint32_t A1k = 0u, B1k = 0u;   // kloop key (wave7 only)
  if (wv == 0){
    const int L = lane;          // columns n=L and n=64+L (L<36)
    // meta -> registers (sorted-rank order); scratch is then overwritable
    int   kpA = ORD[L];
    int   kiA = kpA & 127;
    float uA  = smem[kiA], vA = smem[HID+kiA];
    float cuA = (kpA & 128) ? -uA : uA;   // signed delta for pass2
    float cvA = (kpA & 128) ? -vA : vA;
    int   kpB = 0; float cuB = 0.0f, cvB = 0.0f;
    if (L < 36){
      kpB = ORD[64+L];
      int   kiB = kpB & 127;
      float uB  = smem[kiB], vB = smem[HID+kiB];
      cuB = (kpB & 128) ? -uB : uB;
      cvB = (kpB & 128) ? -vB : vB;
    }
    float a10 = b2[L], a20 = 0.0f;
    float a11 = (L < 36) ? b2[64+L] : 0.0f, a21 = 0.0f;
    // pass 1: rank-0 base = b2 + sum over neg-type features of (+u,+v)*W2row
    for (int rr = 0; rr < HID; ++rr){
      int kp; float cu, cv;
      if (rr < 64){
        kp = __builtin_amdgcn_readlane(kpA, rr);
        cu = __int_as_float(__builtin_amdgcn_readlane(__float_as_int(cuA), rr));
        cv = __int_as_float(__builtin_amdgcn_readlane(__float_as_int(cvA), rr));
      } else {
        kp = __builtin_amdgcn_readlane(kpB, rr-64);
        cu = __int_as_float(__builtin_amdgcn_readlane(__float_as_int(cuB), rr-64));
        cv = __int_as_float(__builtin_amdgcn_readlane(__float_as_int(cvB), rr-64));
      }
      int k = kp & 127;
      float bu = (kp & 128) ? -cu : 0.0f;  // = +u for neg-type, 0 for pos-type
      float bv = (kp & 128) ? -cv : 0.0f;
      float w0 = W2[k*HID + L];
      a10 = fmaf(bu, w0, a10); a20 = fmaf(bv, w0, a20);
      if (L < 36){
        float w1 = W2[k*HID + 64+L];
        a11 = fmaf(bu, w1, a11); a21 = fmaf(bv, w1, a21);
      }
    }
    { float2 f; f.x = a10; f.y = a20; T2D[L] = f; }
    if (L < 36){ float2 f; f.x = a11; f.y = a21; T2D[64+L] = f; }
    // pass 2: ascending ranks, signed deltas, write T[rr+1]
    for (int rr = 0; rr < HID; ++rr){
      int kp; float cu, cv;
      if (rr < 64){
        kp = __builtin_amdgcn_readlane(kpA, rr);
        cu = __int_as_float(__builtin_amdgcn_readlane(__float_as_int(cuA), rr));
        cv = __int_as_float(__builtin_amdgcn_readlane(__float_as_int(cvA), rr));
      } else {
        kp = __builtin_amdgcn_readlane(kpB, rr-64);
        cu = __int_as_float(__builtin_amdgcn_readlane(__float_as_int(cuB), rr-64));
        cv = __int_as_float(__builtin_amdgcn_readlane(__float_as_int(cvB), rr-64));
      }
      int k = kp & 127;
      float w0 = W2[k*HID + L];
      a10 = fmaf(cu, w0, a10); a20 = fmaf(cv, w0, a20);
      { float2 f; f.x = a10; f.y = a20; T2D[(rr+1)*HID + L] = f; }
      if (L < 36){
        float w1 = W2[k*HID + 64+L];
        a11 = fmaf(cu, w1, a11); a21 = fmaf(cv, w1, a21);
        float2 f; f.x = a11; f.y = a21; T2D[(rr+1)*HID + 64+L] = f;
      }
    }
  } else if (wv == 7){
    // key(42) split -> k0=(A0,B0) for iter-0 uniform angles, kloop=(A1,B1)
    uint32_t A0, B0, a1t, b1t;
    tf2x32(0u,42u,0u,2u,A0,a1t);
    tf2x32(0u,42u,1u,3u,B0,b1t);
    A1k = a1t; B1k = b1t;
    if (lane < MCAND){
      uint32_t gidx = (uint32_t)b*MCAND + (uint32_t)lane;
      uint32_t r0, r1, bits;
      if (gidx < 102400u){ tf2x32(A0,B0,gidx,gidx+102400u,r0,r1); bits = r0; }
      else               { tf2x32(A0,B0,gidx-102400u,gidx,r0,r1); bits = r1; }
      SA[lane] = __uint_as_float((bits>>9) | 0x3f800000u) - 1.0f;   // angles0
    }
  }
  __syncthreads();

  // ---------- CEM loop: 99 evaluations ----------
#pragma unroll 1
  for (int t = 0; t < 99; ++t){
    // --- gather phase: q_c = sum_n relu(T1[r][n] + a*T2[r][n]) * W3[n] ---
    if (gact){
      const float av = SA[gc];
      // rank r = #{t_k < a}: split 100 thresholds over 8 lanes, xor-reduce
      int rk = 0;
#pragma unroll
      for (int i = 0; i < 13; ++i){
        int idx = gj*13 + i;
        if (idx < HID) rk += (ST[idx] < av) ? 1 : 0;
      }
      rk += __shfl_xor(rk, 1, 64);
      rk += __shfl_xor(rk, 2, 64);
      rk += __shfl_xor(rk, 4, 64);
      const float2* __restrict__ Trow = T2D + rk*HID;
      float acc = 0.0f;
#pragma unroll
      for (int i = 0; i < 13; ++i){
        int n = gj + (i<<3);
        if (n < HID){
          float2 tv = Trow[n];
          float h = fmaxf(fmaf(av, tv.y, tv.x), 0.0f);
          acc = fmaf(h, w3r[i], acc);
        }
      }
      acc = DPPADD(acc, 0xB1);
      acc = DPPADD(acc, 0x4E);
      acc += __shfl_xor(acc, 4, 64);
      if (gj == 0) SA[gc] = acc;          // q overwrites a (own slot only)
    }
    // --- next-iter eps (wave 7, overlapped with gather) ---
    if (wv == 7 && t < 98){
      uint32_t kk0, kk1;  // keys[t] = (concat[2t], concat[2t+1]) of split(kloop,99)
      { uint32_t i0 = 2u*(uint32_t)t; uint32_t ii = (i0 < 99u) ? i0 : (i0 - 99u);
        uint32_t x, y; tf2x32(A1k,B1k, ii, 99u+ii, x, y); kk0 = (i0 < 99u) ? x : y; }
      { uint32_t i1 = 2u*(uint32_t)t + 1u; uint32_t ii = (i1 < 99u) ? i1 : (i1 - 99u);
        uint32_t x, y; tf2x32(A1k,B1k, ii, 99u+ii, x, y); kk1 = (i1 < 99u) ? x : y; }
      if (lane < MCAND){
        uint32_t gidx = (uint32_t)b*MCAND + (uint32_t)lane;
        uint32_t r0, r1, bits;
        if (gidx < 102400u){ tf2x32(kk0,kk1,gidx,gidx+102400u,r0,r1); bits = r0; }
        else               { tf2x32(kk0,kk1,gidx-102400u,gidx,r0,r1); bits = r1; }
        float fl = __uint_as_float((bits>>9) | 0x3f800000u) - 1.0f;
        float u  = fmaxf(MINV, fl*2.0f + MINV);
        SEPS[lane] = SQRT2 * erfinv32(u);
      }
    }
    __syncthreads();   // B1: all q written; eps(t+1) written

    // --- stats phase (wave 0): top-32 mean/std, then a(t+1) ---
    if (wv == 0){
      float q = -INFINITY;
      if (lane < MCAND) q = SA[lane] + sB3v;
      // sort 32-halves in opposite directions, j=32 max-merge -> top-32 multiset
      float v = q;
#define BST(KK, JJ, PV) { float pv = (PV); bool lower = (lane & (JJ)) == 0; \
        bool asc = (lane & (KK)) != 0; float mn = fminf(v, pv), mx = fmaxf(v, pv); \
        v = (lower == asc) ? mn : mx; }
      BST(2, 1,  DPPPERM(v, 0xB1))
      BST(4, 2,  DPPPERM(v, 0x4E))
      BST(4, 1,  DPPPERM(v, 0xB1))
      BST(8, 4,  __shfl_xor(v, 4, 64))
      BST(8, 2,  DPPPERM(v, 0x4E))
      BST(8, 1,  DPPPERM(v, 0xB1))
      BST(16, 8, __shfl_xor(v, 8, 64))
      BST(16, 4, __shfl_xor(v, 4, 64))
      BST(16, 2, DPPPERM(v, 0x4E))
      BST(16, 1, DPPPERM(v, 0xB1))
      BST(32, 16, __shfl_xor(v, 16, 64))
      BST(32, 8,  __shfl_xor(v, 8, 64))
      BST(32, 4,  __shfl_xor(v, 4, 64))
      BST(32, 2,  DPPPERM(v, 0x4E))
      BST(32, 1,  DPPPERM(v, 0xB1))
#undef BST
      {
        float pv = __shfl_xor(v, 32, 64);
        v = ((lane & 32) == 0) ? fmaxf(v, pv) : fminf(v, pv);
      }
      // sum / sum-of-squares over lanes 0..31 (same add order as before)
      float sv = (lane < NTOP) ? v : 0.0f;
      sv += __shfl_xor(sv, 32, 64);
      sv += __shfl_xor(sv, 16, 64);
      sv += __shfl_xor(sv,  8, 64);
      sv += __shfl_xor(sv,  4, 64);
      sv = DPPADD(sv, 0x4E);
      sv = DPPADD(sv, 0xB1);
      float mun = sv / 32.0f;
      float dv = (lane < NTOP) ? (v - mun) : 0.0f;
      float s2 = dv*dv;
      s2 += __shfl_xor(s2, 32, 64);
      s2 += __shfl_xor(s2, 16, 64);
      s2 += __shfl_xor(s2,  8, 64);
      s2 += __shfl_xor(s2,  4, 64);
      s2 = DPPADD(s2, 0x4E);
      s2 = DPPADD(s2, 0xB1);
      float stdv = sqrtf(s2 / 31.0f);
      if (t == 98){
        if (lane == 0) out[b] = mun * 6.2831854820251465f;  // fp32(2*pi)
      } else if (lane < MCAND){
        SA[lane] = fmaf(stdv, SEPS[lane], mun);             // a(t+1)
      }
    }
    __syncthreads();   // B2: a(t+1) visible to gather
  }
}

extern "C" void kernel_launch(void* const* d_in, const int* in_sizes, int n_in,
                              void* d_out, int out_size, void* d_ws, size_t ws_size,
                              hipStream_t stream) {
  const float* states = (const float*)d_in[0];
  const float* W1     = (const float*)d_in[1];
  const float* b1     = (const float*)d_in[2];
  const float* W2     = (const float*)d_in[3];
  const float* b2     = (const float*)d_in[4];
  const float* W3     = (const float*)d_in[5];
  const float* b3     = (const float*)d_in[6];
  float* out = (float*)d_out;
  hipLaunchKernelGGL(cem_kernel, dim3(BATCH), dim3(512), 0, stream,
                     states, W1, b1, W2, b2, W3, b3, out);
}

// Round 2
// 1620.069 us; speedup vs baseline: 1.3458x; 1.1447x over previous
//
#include <hip/hip_runtime.h>
#include <math.h>
#include <stdint.h>

#define BATCH 4096
#define MCAND 50
#define NTOP 32
#define HID 100

__device__ __forceinline__ uint32_t rotl32(uint32_t v, int d){ return (v<<d)|(v>>(32-d)); }

// JAX threefry2x32 core (20 rounds, 5 key injections)
__device__ __forceinline__ void tf2x32(uint32_t k0, uint32_t k1, uint32_t x0, uint32_t x1,
                                       uint32_t &o0, uint32_t &o1){
  uint32_t k2 = k0 ^ k1 ^ 0x1BD11BDAu;
  x0 += k0; x1 += k1;
#define RND(r) { x0 += x1; x1 = rotl32(x1,(r)); x1 ^= x0; }
  RND(13) RND(15) RND(26) RND(6)
  x0 += k1; x1 += k2 + 1u;
  RND(17) RND(29) RND(16) RND(24)
  x0 += k2; x1 += k0 + 2u;
  RND(13) RND(15) RND(26) RND(6)
  x0 += k0; x1 += k1 + 3u;
  RND(17) RND(29) RND(16) RND(24)
  x0 += k1; x1 += k2 + 4u;
  RND(13) RND(15) RND(26) RND(6)
  x0 += k2; x1 += k0 + 5u;
#undef RND
  o0 = x0; o1 = x1;
}

// XLA ErfInv32 (Giles). w = -log1p(-x*x)
__device__ __forceinline__ float erfinv32(float x){
  float w = -log1pf(-x*x);
  float p;
  if (w < 5.0f){
    w = w - 2.5f;
    p = 2.81022636e-08f;
    p = fmaf(p, w, 3.43273939e-07f);
    p = fmaf(p, w, -3.5233877e-06f);
    p = fmaf(p, w, -4.39150654e-06f);
    p = fmaf(p, w, 0.00021858087f);
    p = fmaf(p, w, -0.00125372503f);
    p = fmaf(p, w, -0.00417768164f);
    p = fmaf(p, w, 0.246640727f);
    p = fmaf(p, w, 1.50140941f);
  } else {
    w = sqrtf(w) - 3.0f;
    p = -0.000200214257f;
    p = fmaf(p, w, 0.000100950558f);
    p = fmaf(p, w, 0.00134934322f);
    p = fmaf(p, w, -0.00367342844f);
    p = fmaf(p, w, 0.00573950773f);
    p = fmaf(p, w, -0.0076224613f);
    p = fmaf(p, w, 0.00943887047f);
    p = fmaf(p, w, 1.00167406f);
    p = fmaf(p, w, 2.83297682f);
  }
  return p*x;
}

// ---- VALU-only lane exchanges (no DS pipe) ----
// DPP quad_perm / row_shl / row_shr / row_ror; permlane{16,32}_swap for 16/32.
#define DPPF(v, CTRL) __int_as_float(__builtin_amdgcn_update_dpp( \
    0, __float_as_int(v), (CTRL), 0xF, 0xF, true))
#define DPPI(v, CTRL) __builtin_amdgcn_update_dpp(0, (v), (CTRL), 0xF, 0xF, true)
#define DPPADD(v, CTRL) ((v) + DPPF((v), (CTRL)))

__device__ __forceinline__ float fswap4(float v){        // v[lane^4]
  float a = DPPF(v, 0x114);   // row_shr:4
  float b = DPPF(v, 0x104);   // row_shl:4
  return (threadIdx.x & 4) ? a : b;
}
__device__ __forceinline__ int iswap4(int v){
  int a = DPPI(v, 0x114), b = DPPI(v, 0x104);
  return (threadIdx.x & 4) ? a : b;
}
__device__ __forceinline__ float fswap8(float v){        // v[lane^8] = row_ror:8
  return DPPF(v, 0x128);
}
__device__ __forceinline__ float fswap16(float v){       // v[lane^16]
#if __has_builtin(__builtin_amdgcn_permlane16_swap)
  auto r = __builtin_amdgcn_permlane16_swap(__float_as_uint(v), __float_as_uint(v), false, false);
  return __uint_as_float((threadIdx.x & 16) ? r[0] : r[1]);
#else
  return __shfl_xor(v, 16, 64);
#endif
}
__device__ __forceinline__ float fswap32(float v){       // v[lane^32]
#if __has_builtin(__builtin_amdgcn_permlane32_swap)
  auto r = __builtin_amdgcn_permlane32_swap(__float_as_uint(v), __float_as_uint(v), false, false);
  return __uint_as_float((threadIdx.x & 32) ? r[0] : r[1]);
#else
  return __shfl_xor(v, 32, 64);
#endif
}

// ---------------------------------------------------------------------------
// Piecewise-linear CEM kernel, single-barrier schedule.
//
// h1[c][k] = relu(u_k + a_c*v_k)  =>  layer-2 pre-activation is piecewise-
// linear in scalar a with fixed breakpoints t_k = -u_k/v_k.  Prefix tables
// over sorted thresholds:  h2pre[n] = T1[r][n] + a*T2[r][n],  r = #{t_k < a}.
//
// Schedule per iteration (ONE barrier):
//   G: waves 0-6 gather q(t) -> QBUF[t&1]; wave 7 RNG eps(t+1) -> EPS[(t+1)&1]
//   barrier
//   S: waves 0-6 REDUNDANTLY compute top-32 mu/std (VALU-only bitonic) and
//      each lane forms its own a(t+1) in-register.  Ping-pong buffers make
//      the cross-iteration overlaps race-free.
// All cross-lane ops are DPP/permlane (VALU) — no ds_bpermute chains.
// LDS: T(80,800B) + eps 2x50 + q 2x50 = 81,600B -> 2 blocks/CU.
// ---------------------------------------------------------------------------

__global__ __launch_bounds__(512, 4) void cem_kernel(
    const float* __restrict__ states, const float* __restrict__ W1,
    const float* __restrict__ b1,     const float* __restrict__ W2,
    const float* __restrict__ b2,     const float* __restrict__ W3,
    const float* __restrict__ b3,     float* __restrict__ out)
{
  __shared__ __align__(16) float smem[20400];           // 81,600 B
  float2* const T2D  = (float2*)smem;                   // [101][100] (T1,T2)
  int*    const ORD  = (int*)(smem + 300);              // init scratch (in T)
  float*  const ST   = smem + 400;                      // init scratch (in T)
  float*  const EPBa = smem + 20200;                    // [2][50] eps ping-pong
  float*  const QBa  = smem + 20300;                    // [2][50] q ping-pong

  const int tid  = threadIdx.x;
  const int b    = blockIdx.x;
  const int wv   = tid >> 6;
  const int lane = tid & 63;
  const int gc   = tid >> 3;            // gather candidate (8 lanes/cand)
  const int gj   = tid & 7;
  const bool gact = (tid < 8*MCAND);    // tid < 400

  const float MINV  = -0x1.fffffep-1f;  // nextafter(-1,0)
  const float SQRT2 = 0x1.6a09e6p+0f;   // fp32 sqrt(2)

  // per-thread W3 slice for the gather (n = gj + 8i)
  float w3r[13];
#pragma unroll
  for (int i = 0; i < 13; ++i){
    int n = gj + (i<<3);
    w3r[i] = (n < HID) ? W3[n] : 0.0f;
  }
  const float sB3v = b3[0];

  // ---------- init P0: u, v, thresholds ----------
  if (tid < HID){
    float u = fmaf(states[2*b], W1[tid], fmaf(states[2*b+1], W1[HID+tid], b1[tid]));
    float v = W1[2*HID+tid];
    float tt = (v != 0.0f) ? (-u / v) : INFINITY;
    smem[tid]     = u;
    smem[HID+tid] = v;
    smem[200+tid] = tt;
  }
  __syncthreads();

  // ---------- init P1: stable rank-by-count, scatter sorted ----------
  if (tid < HID){
    float tk = smem[200+tid];
    int rk = 0;
    for (int j2 = 0; j2 < HID; ++j2){
      float tj = smem[200+j2];
      rk += (tj < tk || (tj == tk && j2 < tid)) ? 1 : 0;
    }
    float u = smem[tid], v = smem[HID+tid];
    // neg-type: active iff a < t (v<0, or v==0 with u>0 -> always active, t=+inf)
    int neg = (v < 0.0f || (v == 0.0f && u > 0.0f)) ? 1 : 0;
    ST[rk]  = tk;
    ORD[rk] = tid | (neg << 7);
  }
  __syncthreads();

  // ---------- init P1.5: meta -> registers (wave0) + thresholds -> regs (all) ----------
  int kpA = 0, kpB = 0; float cuA = 0.f, cvA = 0.f, cuB = 0.f, cvB = 0.f;
  if (wv == 0){
    kpA = ORD[lane];
    int kiA = kpA & 127;
    float uA = smem[kiA], vA = smem[HID+kiA];
    cuA = (kpA & 128) ? -uA : uA;     // signed delta for prefix pass
    cvA = (kpA & 128) ? -vA : vA;
    if (lane < 36){
      kpB = ORD[64+lane];
      int kiB = kpB & 127;
      float uB = smem[kiB], vB = smem[HID+kiB];
      cuB = (kpB & 128) ? -uB : uB;
      cvB = (kpB & 128) ? -vB : vB;
    }
  }
  float st_r[13];                       // loop-invariant thresholds in regs
#pragma unroll
  for (int i = 0; i < 13; ++i){
    int idx = gj*13 + i;
    st_r[i] = (idx < HID) ? ST[idx] : INFINITY;
  }
  __syncthreads();   // meta/thresholds consumed; T scratch region now dead

  // ---------- init P2: wave0 builds prefix tables; wave7 RNG setup ----------
  uint32_t A1k = 0u, B1k = 0u;   // kloop key (wave7 only)
  if (wv == 0){
    const int L = lane;          // columns n=L and n=64+L (L<36)
    float a10 = b2[L], a20 = 0.0f;
    float a11 = (L < 36) ? b2[64+L] : 0.0f, a21 = 0.0f;
    // pass 1: rank-0 base = b2 + sum over neg-type features of (+u,+v)*W2row
#pragma unroll 8
    for (int rr = 0; rr < 64; ++rr){
      int   kp = __builtin_amdgcn_readlane(kpA, rr);
      float cu = __int_as_float(__builtin_amdgcn_readlane(__float_as_int(cuA), rr));
      float cv = __int_as_float(__builtin_amdgcn_readlane(__float_as_int(cvA), rr));
      int k = kp & 127;
      float bu = (kp & 128) ? -cu : 0.0f;  // = +u for neg-type, 0 for pos-type
      float bv = (kp & 128) ? -cv : 0.0f;
      float w0 = W2[k*HID + L];
      a10 = fmaf(bu, w0, a10); a20 = fmaf(bv, w0, a20);
      if (L < 36){
        float w1 = W2[k*HID + 64+L];
        a11 = fmaf(bu, w1, a11); a21 = fmaf(bv, w1, a21);
      }
    }
#pragma unroll 6
    for (int rr = 0; rr < 36; ++rr){
      int   kp = __builtin_amdgcn_readlane(kpB, rr);
      float cu = __int_as_float(__builtin_amdgcn_readlane(__float_as_int(cuB), rr));
      float cv = __int_as_float(__builtin_amdgcn_readlane(__float_as_int(cvB), rr));
      int k = kp & 127;
      float bu = (kp & 128) ? -cu : 0.0f;
      float bv = (kp & 128) ? -cv : 0.0f;
      float w0 = W2[k*HID + L];
      a10 = fmaf(bu, w0, a10); a20 = fmaf(bv, w0, a20);
      if (L < 36){
        float w1 = W2[k*HID + 64+L];
        a11 = fmaf(bu, w1, a11); a21 = fmaf(bv, w1, a21);
      }
    }
    { float2 f; f.x = a10; f.y = a20; T2D[L] = f; }
    if (L < 36){ float2 f; f.x = a11; f.y = a21; T2D[64+L] = f; }
    // pass 2: ascending ranks, signed deltas, write T[rr+1]
#pragma unroll 8
    for (int rr = 0; rr < 64; ++rr){
      int   kp = __builtin_amdgcn_readlane(kpA, rr);
      float cu = __int_as_float(__builtin_amdgcn_readlane(__float_as_int(cuA), rr));
      float cv = __int_as_float(__builtin_amdgcn_readlane(__float_as_int(cvA), rr));
      int k = kp & 127;
      float w0 = W2[k*HID + L];
      a10 = fmaf(cu, w0, a10); a20 = fmaf(cv, w0, a20);
      { float2 f; f.x = a10; f.y = a20; T2D[(rr+1)*HID + L] = f; }
      if (L < 36){
        float w1 = W2[k*HID + 64+L];
        a11 = fmaf(cu, w1, a11); a21 = fmaf(cv, w1, a21);
        float2 f; f.x = a11; f.y = a21; T2D[(rr+1)*HID + 64+L] = f;
      }
    }
#pragma unroll 6
    for (int rr = 0; rr < 36; ++rr){
      int   kp = __builtin_amdgcn_readlane(kpB, rr);
      float cu = __int_as_float(__builtin_amdgcn_readlane(__float_as_int(cuB), rr));
      float cv = __int_as_float(__builtin_amdgcn_readlane(__float_as_int(cvB), rr));
      int k = kp & 127;
      float w0 = W2[k*HID + L];
      a10 = fmaf(cu, w0, a10); a20 = fmaf(cv, w0, a20);
      { float2 f; f.x = a10; f.y = a20; T2D[(65+rr)*HID + L] = f; }
      if (L < 36){
        float w1 = W2[k*HID + 64+L];
        a11 = fmaf(cu, w1, a11); a21 = fmaf(cv, w1, a21);
        float2 f; f.x = a11; f.y = a21; T2D[(65+rr)*HID + 64+L] = f;
      }
    }
  } else if (wv == 7){
    // key(42) split -> k0=(A0,B0) for iter-0 uniform angles, kloop=(A1,B1)
    uint32_t A0, B0, a1t, b1t;
    tf2x32(0u,42u,0u,2u,A0,a1t);
    tf2x32(0u,42u,1u,3u,B0,b1t);
    A1k = a1t; B1k = b1t;
    if (lane < MCAND){
      uint32_t gidx = (uint32_t)b*MCAND + (uint32_t)lane;
      uint32_t r0, r1, bits;
      if (gidx < 102400u){ tf2x32(A0,B0,gidx,gidx+102400u,r0,r1); bits = r0; }
      else               { tf2x32(A0,B0,gidx-102400u,gidx,r0,r1); bits = r1; }
      EPBa[lane] = __uint_as_float((bits>>9) | 0x3f800000u) - 1.0f;   // angles0
    }
  }
  __syncthreads();

  float av = 0.0f;
  if (gact) av = EPBa[gc];              // iteration-0 angles (mu=0, std=1)

  // ---------- CEM loop: 99 evaluations, ONE barrier each ----------
#pragma unroll 1
  for (int t = 0; t < 99; ++t){
    const int par = t & 1;
    // --- G: q_c = sum_n relu(T1[r][n] + a*T2[r][n]) * W3[n] ---
    if (gact){
      int rk = 0;
#pragma unroll
      for (int i = 0; i < 13; ++i) rk += (st_r[i] < av) ? 1 : 0;
      rk += DPPI(rk, 0xB1);
      rk += DPPI(rk, 0x4E);
      rk += iswap4(rk);
      const float2* __restrict__ Trow = T2D + rk*HID;
      float acc = 0.0f;
#pragma unroll
      for (int i = 0; i < 13; ++i){
        int n = gj + (i<<3);
        n = (n < HID) ? n : gj;         // clamp (w3r=0 there; avoids inf*0)
        float2 tv = Trow[n];
        float h = fmaxf(fmaf(av, tv.y, tv.x), 0.0f);
        acc = fmaf(h, w3r[i], acc);
      }
      acc = DPPADD(acc, 0xB1);
      acc = DPPADD(acc, 0x4E);
      acc += fswap4(acc);
      if (gj == 0) QBa[par*50 + gc] = acc;
    }
    // --- next-iter eps (wave 7, overlapped with gather) ---
    if (wv == 7 && t < 98){
      uint32_t kk0, kk1;  // keys[t] = (concat[2t], concat[2t+1]) of split(kloop,99)
      { uint32_t i0 = 2u*(uint32_t)t; uint32_t ii = (i0 < 99u) ? i0 : (i0 - 99u);
        uint32_t x, y; tf2x32(A1k,B1k, ii, 99u+ii, x, y); kk0 = (i0 < 99u) ? x : y; }
      { uint32_t i1 = 2u*(uint32_t)t + 1u; uint32_t ii = (i1 < 99u) ? i1 : (i1 - 99u);
        uint32_t x, y; tf2x32(A1k,B1k, ii, 99u+ii, x, y); kk1 = (i1 < 99u) ? x : y; }
      if (lane < MCAND){
        uint32_t gidx = (uint32_t)b*MCAND + (uint32_t)lane;
        uint32_t r0, r1, bits;
        if (gidx < 102400u){ tf2x32(kk0,kk1,gidx,gidx+102400u,r0,r1); bits = r0; }
        else               { tf2x32(kk0,kk1,gidx-102400u,gidx,r0,r1); bits = r1; }
        float fl = __uint_as_float((bits>>9) | 0x3f800000u) - 1.0f;
        float u  = fmaxf(MINV, fl*2.0f + MINV);
        EPBa[((t+1)&1)*50 + lane] = SQRT2 * erfinv32(u);
      }
    }
    __syncthreads();   // B1: q(t) + eps(t+1) visible

    // --- S: redundant per-wave top-32 stats (VALU-only), a(t+1) in-register ---
    if (wv < 7){
      float q = -INFINITY;
      if (lane < MCAND) q = QBa[par*50 + lane] + sB3v;
      // sort 32-halves in opposite directions, j=32 max-merge -> top-32 multiset
      float v = q;
#define BST(KK, JJ, PV) { float pv = (PV); bool lower = (lane & (JJ)) == 0; \
        bool asc = (lane & (KK)) != 0; float mn = fminf(v, pv), mx = fmaxf(v, pv); \
        v = (lower == asc) ? mn : mx; }
      BST(2, 1,  DPPF(v, 0xB1))
      BST(4, 2,  DPPF(v, 0x4E))
      BST(4, 1,  DPPF(v, 0xB1))
      BST(8, 4,  fswap4(v))
      BST(8, 2,  DPPF(v, 0x4E))
      BST(8, 1,  DPPF(v, 0xB1))
      BST(16, 8, fswap8(v))
      BST(16, 4, fswap4(v))
      BST(16, 2, DPPF(v, 0x4E))
      BST(16, 1, DPPF(v, 0xB1))
      BST(32, 16, fswap16(v))
      BST(32, 8,  fswap8(v))
      BST(32, 4,  fswap4(v))
      BST(32, 2,  DPPF(v, 0x4E))
      BST(32, 1,  DPPF(v, 0xB1))
#undef BST
      {
        float pv = fswap32(v);
        v = ((lane & 32) == 0) ? fmaxf(v, pv) : fminf(v, pv);
      }
      // sum / sum-of-squares over lanes 0..31 (same add order as before)
      float sv = (lane < NTOP) ? v : 0.0f;
      sv += fswap32(sv);
      sv += fswap16(sv);
      sv += fswap8(sv);
      sv += fswap4(sv);
      sv = DPPADD(sv, 0x4E);
      sv = DPPADD(sv, 0xB1);
      float mun = sv / 32.0f;
      float dv = (lane < NTOP) ? (v - mun) : 0.0f;
      float s2 = dv*dv;
      s2 += fswap32(s2);
      s2 += fswap16(s2);
      s2 += fswap8(s2);
      s2 += fswap4(s2);
      s2 = DPPADD(s2, 0x4E);
      s2 = DPPADD(s2, 0xB1);
      float stdv = sqrtf(s2 / 31.0f);
      if (t == 98){
        if (tid == 0) out[b] = mun * 6.2831854820251465f;  // fp32(2*pi)
      } else if (gact){
        av = fmaf(stdv, EPBa[((t+1)&1)*50 + gc], mun);     // a(t+1), in-register
      }
    }
    // no second barrier: QBUF/EPS ping-pong + program order make
    // G(t+1) writes (parity ^1) disjoint from S(t) reads (parity t&1).
  }
}

extern "C" void kernel_launch(void* const* d_in, const int* in_sizes, int n_in,
                              void* d_out, int out_size, void* d_ws, size_t ws_size,
                              hipStream_t stream) {
  const float* states = (const float*)d_in[0];
  const float* W1     = (const float*)d_in[1];
  const float* b1     = (const float*)d_in[2];
  const float* W2     = (const float*)d_in[3];
  const float* b2     = (const float*)d_in[4];
  const float* W3     = (const float*)d_in[5];
  const float* b3     = (const float*)d_in[6];
  float* out = (float*)d_out;
  hipLaunchKernelGGL(cem_kernel, dim3(BATCH), dim3(512), 0, stream,
                     states, W1, b1, W2, b2, W3, b3, out);
}

// Round 3
// 1314.739 us; speedup vs baseline: 1.6583x; 1.2322x over previous
//
#include <hip/hip_runtime.h>
#include <math.h>
#include <stdint.h>

#define BATCH 4096
#define MCAND 50
#define NTOP 32
#define HID 100
#define EPS_ROWS 98
#define EPS_ROWSZ (BATCH*MCAND)              /* 204800 */
#define EPS_ELEMS (EPS_ROWS*EPS_ROWSZ)       /* 20,070,400 */
#define WS_NEED   (1024u + (size_t)EPS_ELEMS*4u)

#define MINVC  (-0x1.fffffep-1f)   /* nextafter(-1,0) */
#define SQRT2C (0x1.6a09e6p+0f)    /* fp32 sqrt(2) */

__device__ __forceinline__ uint32_t rotl32(uint32_t v, int d){ return (v<<d)|(v>>(32-d)); }

// JAX threefry2x32 core (20 rounds, 5 key injections)
__device__ __forceinline__ void tf2x32(uint32_t k0, uint32_t k1, uint32_t x0, uint32_t x1,
                                       uint32_t &o0, uint32_t &o1){
  uint32_t k2 = k0 ^ k1 ^ 0x1BD11BDAu;
  x0 += k0; x1 += k1;
#define RND(r) { x0 += x1; x1 = rotl32(x1,(r)); x1 ^= x0; }
  RND(13) RND(15) RND(26) RND(6)
  x0 += k1; x1 += k2 + 1u;
  RND(17) RND(29) RND(16) RND(24)
  x0 += k2; x1 += k0 + 2u;
  RND(13) RND(15) RND(26) RND(6)
  x0 += k0; x1 += k1 + 3u;
  RND(17) RND(29) RND(16) RND(24)
  x0 += k1; x1 += k2 + 4u;
  RND(13) RND(15) RND(26) RND(6)
  x0 += k2; x1 += k0 + 5u;
#undef RND
  o0 = x0; o1 = x1;
}

// XLA ErfInv32 (Giles). w = -log1p(-x*x)
__device__ __forceinline__ float erfinv32(float x){
  float w = -log1pf(-x*x);
  float p;
  if (w < 5.0f){
    w = w - 2.5f;
    p = 2.81022636e-08f;
    p = fmaf(p, w, 3.43273939e-07f);
    p = fmaf(p, w, -3.5233877e-06f);
    p = fmaf(p, w, -4.39150654e-06f);
    p = fmaf(p, w, 0.00021858087f);
    p = fmaf(p, w, -0.00125372503f);
    p = fmaf(p, w, -0.00417768164f);
    p = fmaf(p, w, 0.246640727f);
    p = fmaf(p, w, 1.50140941f);
  } else {
    w = sqrtf(w) - 3.0f;
    p = -0.000200214257f;
    p = fmaf(p, w, 0.000100950558f);
    p = fmaf(p, w, 0.00134934322f);
    p = fmaf(p, w, -0.00367342844f);
    p = fmaf(p, w, 0.00573950773f);
    p = fmaf(p, w, -0.0076224613f);
    p = fmaf(p, w, 0.00943887047f);
    p = fmaf(p, w, 1.00167406f);
    p = fmaf(p, w, 2.83297682f);
  }
  return p*x;
}

// ---- VALU-only lane exchanges (no DS pipe) ----
#define DPPF(v, CTRL) __int_as_float(__builtin_amdgcn_update_dpp( \
    0, __float_as_int(v), (CTRL), 0xF, 0xF, true))
#define DPPI(v, CTRL) __builtin_amdgcn_update_dpp(0, (v), (CTRL), 0xF, 0xF, true)
#define DPPADD(v, CTRL) ((v) + DPPF((v), (CTRL)))

__device__ __forceinline__ float fswap4(float v){        // v[lane^4]
  float a = DPPF(v, 0x114);   // row_shr:4
  float b = DPPF(v, 0x104);   // row_shl:4
  return (threadIdx.x & 4) ? a : b;
}
__device__ __forceinline__ int iswap4(int v){
  int a = DPPI(v, 0x114), b = DPPI(v, 0x104);
  return (threadIdx.x & 4) ? a : b;
}
__device__ __forceinline__ float fswap8(float v){        // v[lane^8] = row_ror:8
  return DPPF(v, 0x128);
}
__device__ __forceinline__ float fswap16(float v){       // v[lane^16]
#if __has_builtin(__builtin_amdgcn_permlane16_swap)
  auto r = __builtin_amdgcn_permlane16_swap(__float_as_uint(v), __float_as_uint(v), false, false);
  return __uint_as_float((threadIdx.x & 16) ? r[0] : r[1]);
#else
  return __shfl_xor(v, 16, 64);
#endif
}
__device__ __forceinline__ float fswap32(float v){       // v[lane^32]
#if __has_builtin(__builtin_amdgcn_permlane32_swap)
  auto r = __builtin_amdgcn_permlane32_swap(__float_as_uint(v), __float_as_uint(v), false, false);
  return __uint_as_float((threadIdx.x & 32) ? r[0] : r[1]);
#else
  return __shfl_xor(v, 32, 64);
#endif
}

// ---------------------------------------------------------------------------
// Pre-kernels: loop RNG is block-independent -> compute the whole eps tensor
// eps[t][b][c] (t=0..97 -> used at a(t+1)) in parallel instead of 1 wave/block.
// Bit-identical threefry/erfinv to the in-loop version.
// ---------------------------------------------------------------------------
__global__ void keys_kernel(uint32_t* __restrict__ K){
  int tid = threadIdx.x;
  if (tid < 99){
    uint32_t A0, B0, A1, B1;
    tf2x32(0u,42u,0u,2u,A0,A1);
    tf2x32(0u,42u,1u,3u,B0,B1);
    (void)A0; (void)B0;
    uint32_t o0,o1;
    tf2x32(A1,B1,(uint32_t)tid,(uint32_t)(99+tid),o0,o1);
    K[tid]    = o0;
    K[99+tid] = o1;
  }
}

__global__ __launch_bounds__(256) void eps_kernel(const uint32_t* __restrict__ K,
                                                  float* __restrict__ E){
  int id = blockIdx.x*256 + threadIdx.x;           // grid sized exactly
  int t  = id / EPS_ROWSZ;                          // const-div -> magic mul
  int g  = id - t*EPS_ROWSZ;                        // g = b*50+lane = gidx
  uint32_t kk0 = K[2*t], kk1 = K[2*t+1];
  uint32_t r0, r1, bits;
  if ((uint32_t)g < 102400u){ tf2x32(kk0,kk1,(uint32_t)g,(uint32_t)g+102400u,r0,r1); bits = r0; }
  else                      { tf2x32(kk0,kk1,(uint32_t)g-102400u,(uint32_t)g,r0,r1); bits = r1; }
  float fl = __uint_as_float((bits>>9) | 0x3f800000u) - 1.0f;
  float u  = fmaxf(MINVC, fl*2.0f + MINVC);
  E[id] = SQRT2C * erfinv32(u);
}

// ---------------------------------------------------------------------------
// Piecewise-linear CEM kernel, centralized stats.
//   h2pre[n] = T1[r][n] + a*T2[r][n],  r = #{t_k < a}  (prefix tables, exact fp32)
// Per iteration:
//   G: waves 0-6 gather q(t) (a read from LDS A[]); wave0 prefetches eps(t+1)
//      [fallback: wave7 computes eps(t+1) -> EPB]
//   B1
//   S: wave 0 ONLY: top-32 mu/std (VALU bitonic), writes A[] = a(t+1)
//   B2
// Single-buffer A/QB/EPB are race-free under the two barriers.
// LDS: T(80,800B)+A+QB+EPB = 81,600B -> 2 blocks/CU.
// ---------------------------------------------------------------------------
template<bool EPSG>
__global__ __launch_bounds__(512, 4) void cem_kernel(
    const float* __restrict__ states, const float* __restrict__ W1,
    const float* __restrict__ b1,     const float* __restrict__ W2,
    const float* __restrict__ b2,     const float* __restrict__ W3,
    const float* __restrict__ b3,     const float* __restrict__ epsg,
    float* __restrict__ out)
{
  __shared__ __align__(16) float smem[20400];           // 81,600 B
  float2* const T2D  = (float2*)smem;                   // [101][100] (T1,T2)
  int*    const ORD  = (int*)(smem + 300);              // init scratch (in T)
  float*  const ST   = smem + 400;                      // init scratch (in T)
  float*  const A    = smem + 20200;                    // [50] current angles
  float*  const QB   = smem + 20250;                    // [50] q values
  float*  const EPB  = smem + 20300;                    // [50] eps (fallback)

  const int tid  = threadIdx.x;
  const int b    = blockIdx.x;
  const int wv   = tid >> 6;
  const int lane = tid & 63;
  const int gc   = tid >> 3;            // gather candidate (8 lanes/cand)
  const int gj   = tid & 7;
  const bool gact = (tid < 8*MCAND);    // tid < 400 (waves 0-6)

  // per-thread W3 slice for the gather (n = gj + 8i)
  float w3r[13];
#pragma unroll
  for (int i = 0; i < 13; ++i){
    int n = gj + (i<<3);
    w3r[i] = (n < HID) ? W3[n] : 0.0f;
  }
  const float sB3v = b3[0];

  // ---------- init P0: u, v, thresholds ----------
  if (tid < HID){
    float u = fmaf(states[2*b], W1[tid], fmaf(states[2*b+1], W1[HID+tid], b1[tid]));
    float v = W1[2*HID+tid];
    float tt = (v != 0.0f) ? (-u / v) : INFINITY;
    smem[tid]     = u;
    smem[HID+tid] = v;
    smem[200+tid] = tt;
  }
  __syncthreads();

  // ---------- init P1: stable rank-by-count, scatter sorted ----------
  if (tid < HID){
    float tk = smem[200+tid];
    int rk = 0;
    for (int j2 = 0; j2 < HID; ++j2){
      float tj = smem[200+j2];
      rk += (tj < tk || (tj == tk && j2 < tid)) ? 1 : 0;
    }
    float u = smem[tid], v = smem[HID+tid];
    // neg-type: active iff a < t (v<0, or v==0 with u>0 -> always active, t=+inf)
    int neg = (v < 0.0f || (v == 0.0f && u > 0.0f)) ? 1 : 0;
    ST[rk]  = tk;
    ORD[rk] = tid | (neg << 7);
  }
  __syncthreads();

  // ---------- init P1.5: meta -> registers (wave0) + thresholds -> regs ----------
  int kpA = 0, kpB = 0; float cuA = 0.f, cvA = 0.f, cuB = 0.f, cvB = 0.f;
  if (wv == 0){
    kpA = ORD[lane];
    int kiA = kpA & 127;
    float uA = smem[kiA], vA = smem[HID+kiA];
    cuA = (kpA & 128) ? -uA : uA;     // signed delta for prefix pass
    cvA = (kpA & 128) ? -vA : vA;
    if (lane < 36){
      kpB = ORD[64+lane];
      int kiB = kpB & 127;
      float uB = smem[kiB], vB = smem[HID+kiB];
      cuB = (kpB & 128) ? -uB : uB;
      cvB = (kpB & 128) ? -vB : vB;
    }
  }
  float st_r[13];                       // loop-invariant thresholds in regs
#pragma unroll
  for (int i = 0; i < 13; ++i){
    int idx = gj*13 + i;
    st_r[i] = (idx < HID) ? ST[idx] : INFINITY;
  }
  __syncthreads();   // meta/thresholds consumed; T scratch region now dead

  // ---------- init P2: wave0 builds prefix tables; wave7 iter-0 angles ----------
  uint32_t A1k = 0u, B1k = 0u;   // kloop key (fallback wave7 only)
  if (wv == 0){
    const int L = lane;          // columns n=L and n=64+L (L<36)
    float a10 = b2[L], a20 = 0.0f;
    float a11 = (L < 36) ? b2[64+L] : 0.0f, a21 = 0.0f;
    // pass 1: rank-0 base = b2 + sum over neg-type features of (+u,+v)*W2row
#pragma unroll 8
    for (int rr = 0; rr < 64; ++rr){
      int   kp = __builtin_amdgcn_readlane(kpA, rr);
      float cu = __int_as_float(__builtin_amdgcn_readlane(__float_as_int(cuA), rr));
      float cv = __int_as_float(__builtin_amdgcn_readlane(__float_as_int(cvA), rr));
      int k = kp & 127;
      float bu = (kp & 128) ? -cu : 0.0f;  // = +u for neg-type, 0 for pos-type
      float bv = (kp & 128) ? -cv : 0.0f;
      float w0 = W2[k*HID + L];
      a10 = fmaf(bu, w0, a10); a20 = fmaf(bv, w0, a20);
      if (L < 36){
        float w1 = W2[k*HID + 64+L];
        a11 = fmaf(bu, w1, a11); a21 = fmaf(bv, w1, a21);
      }
    }
#pragma unroll 6
    for (int rr = 0; rr < 36; ++rr){
      int   kp = __builtin_amdgcn_readlane(kpB, rr);
      float cu = __int_as_float(__builtin_amdgcn_readlane(__float_as_int(cuB), rr));
      float cv = __int_as_float(__builtin_amdgcn_readlane(__float_as_int(cvB), rr));
      int k = kp & 127;
      float bu = (kp & 128) ? -cu : 0.0f;
      float bv = (kp & 128) ? -cv : 0.0f;
      float w0 = W2[k*HID + L];
      a10 = fmaf(bu, w0, a10); a20 = fmaf(bv, w0, a20);
      if (L < 36){
        float w1 = W2[k*HID + 64+L];
        a11 = fmaf(bu, w1, a11); a21 = fmaf(bv, w1, a21);
      }
    }
    { float2 f; f.x = a10; f.y = a20; T2D[L] = f; }
    if (L < 36){ float2 f; f.x = a11; f.y = a21; T2D[64+L] = f; }
    // pass 2: ascending ranks, signed deltas, write T[rr+1]
#pragma unroll 8
    for (int rr = 0; rr < 64; ++rr){
      int   kp = __builtin_amdgcn_readlane(kpA, rr);
      float cu = __int_as_float(__builtin_amdgcn_readlane(__float_as_int(cuA), rr));
      float cv = __int_as_float(__builtin_amdgcn_readlane(__float_as_int(cvA), rr));
      int k = kp & 127;
      float w0 = W2[k*HID + L];
      a10 = fmaf(cu, w0, a10); a20 = fmaf(cv, w0, a20);
      { float2 f; f.x = a10; f.y = a20; T2D[(rr+1)*HID + L] = f; }
      if (L < 36){
        float w1 = W2[k*HID + 64+L];
        a11 = fmaf(cu, w1, a11); a21 = fmaf(cv, w1, a21);
        float2 f; f.x = a11; f.y = a21; T2D[(rr+1)*HID + 64+L] = f;
      }
    }
#pragma unroll 6
    for (int rr = 0; rr < 36; ++rr){
      int   kp = __builtin_amdgcn_readlane(kpB, rr);
      float cu = __int_as_float(__builtin_amdgcn_readlane(__float_as_int(cuB), rr));
      float cv = __int_as_float(__builtin_amdgcn_readlane(__float_as_int(cvB), rr));
      int k = kp & 127;
      float w0 = W2[k*HID + L];
      a10 = fmaf(cu, w0, a10); a20 = fmaf(cv, w0, a20);
      { float2 f; f.x = a10; f.y = a20; T2D[(65+rr)*HID + L] = f; }
      if (L < 36){
        float w1 = W2[k*HID + 64+L];
        a11 = fmaf(cu, w1, a11); a21 = fmaf(cv, w1, a21);
        float2 f; f.x = a11; f.y = a21; T2D[(65+rr)*HID + 64+L] = f;
      }
    }
  } else if (wv == 7){
    // key(42) split -> k0=(A0,B0) iter-0 uniform angles; kloop=(A1,B1) fallback
    uint32_t A0, B0, a1t, b1t;
    tf2x32(0u,42u,0u,2u,A0,a1t);
    tf2x32(0u,42u,1u,3u,B0,b1t);
    A1k = a1t; B1k = b1t;
    if (lane < MCAND){
      uint32_t gidx = (uint32_t)b*MCAND + (uint32_t)lane;
      uint32_t r0, r1, bits;
      if (gidx < 102400u){ tf2x32(A0,B0,gidx,gidx+102400u,r0,r1); bits = r0; }
      else               { tf2x32(A0,B0,gidx-102400u,gidx,r0,r1); bits = r1; }
      A[lane] = __uint_as_float((bits>>9) | 0x3f800000u) - 1.0f;   // angles0
    }
  }
  __syncthreads();

  // ---------- CEM loop: 99 evaluations ----------
#pragma unroll 1
  for (int t = 0; t < 99; ++t){
    // eps prefetch for a(t+1) (EPSG path; hidden under gather + B1)
    float epsv = 0.0f;
    if (EPSG){
      if (wv == 0 && lane < MCAND && t < EPS_ROWS)
        epsv = epsg[(size_t)t*EPS_ROWSZ + (size_t)b*MCAND + (size_t)lane];
    }
    // --- G: q_c = sum_n relu(T1[r][n] + a*T2[r][n]) * W3[n] ---
    if (gact){
      const float av = A[gc];             // LDS broadcast (8 lanes same addr)
      int rk = 0;
#pragma unroll
      for (int i = 0; i < 13; ++i) rk += (st_r[i] < av) ? 1 : 0;
      rk += DPPI(rk, 0xB1);
      rk += DPPI(rk, 0x4E);
      rk += iswap4(rk);
      const float2* __restrict__ Trow = T2D + rk*HID;
      float acc = 0.0f;
#pragma unroll
      for (int i = 0; i < 13; ++i){
        int n = gj + (i<<3);
        n = (n < HID) ? n : gj;           // clamp (w3r=0 there; avoids inf*0)
        float2 tv = Trow[n];
        float h = fmaxf(fmaf(av, tv.y, tv.x), 0.0f);
        acc = fmaf(h, w3r[i], acc);
      }
      acc = DPPADD(acc, 0xB1);
      acc = DPPADD(acc, 0x4E);
      acc += fswap4(acc);
      if (gj == 0) QB[gc] = acc;
    }
    // --- fallback: next-iter eps on wave 7 (overlapped with gather) ---
    if (!EPSG && wv == 7 && t < EPS_ROWS){
      uint32_t kk0, kk1;  // keys[t] = (concat[2t], concat[2t+1]) of split(kloop,99)
      { uint32_t i0 = 2u*(uint32_t)t; uint32_t ii = (i0 < 99u) ? i0 : (i0 - 99u);
        uint32_t x, y; tf2x32(A1k,B1k, ii, 99u+ii, x, y); kk0 = (i0 < 99u) ? x : y; }
      { uint32_t i1 = 2u*(uint32_t)t + 1u; uint32_t ii = (i1 < 99u) ? i1 : (i1 - 99u);
        uint32_t x, y; tf2x32(A1k,B1k, ii, 99u+ii, x, y); kk1 = (i1 < 99u) ? x : y; }
      if (lane < MCAND){
        uint32_t gidx = (uint32_t)b*MCAND + (uint32_t)lane;
        uint32_t r0, r1, bits;
        if (gidx < 102400u){ tf2x32(kk0,kk1,gidx,gidx+102400u,r0,r1); bits = r0; }
        else               { tf2x32(kk0,kk1,gidx-102400u,gidx,r0,r1); bits = r1; }
        float fl = __uint_as_float((bits>>9) | 0x3f800000u) - 1.0f;
        float u  = fmaxf(MINVC, fl*2.0f + MINVC);
        EPB[lane] = SQRT2C * erfinv32(u);
      }
    }
    __syncthreads();   // B1: q(t) + eps(t+1) visible

    // --- S: wave 0 only — top-32 stats (VALU bitonic), write a(t+1) ---
    if (wv == 0){
      float q = (lane < MCAND) ? (QB[lane] + sB3v) : -INFINITY;
      // sort 32-halves in opposite directions, j=32 max-merge -> top-32 multiset
      float v = q;
#define BST(KK, JJ, PV) { float pv = (PV); bool lower = (lane & (JJ)) == 0; \
        bool asc = (lane & (KK)) != 0; float mn = fminf(v, pv), mx = fmaxf(v, pv); \
        v = (lower == asc) ? mn : mx; }
      BST(2, 1,  DPPF(v, 0xB1))
      BST(4, 2,  DPPF(v, 0x4E))
      BST(4, 1,  DPPF(v, 0xB1))
      BST(8, 4,  fswap4(v))
      BST(8, 2,  DPPF(v, 0x4E))
      BST(8, 1,  DPPF(v, 0xB1))
      BST(16, 8, fswap8(v))
      BST(16, 4, fswap4(v))
      BST(16, 2, DPPF(v, 0x4E))
      BST(16, 1, DPPF(v, 0xB1))
      BST(32, 16, fswap16(v))
      BST(32, 8,  fswap8(v))
      BST(32, 4,  fswap4(v))
      BST(32, 2,  DPPF(v, 0x4E))
      BST(32, 1,  DPPF(v, 0xB1))
#undef BST
      {
        float pv = fswap32(v);
        v = ((lane & 32) == 0) ? fmaxf(v, pv) : fminf(v, pv);
      }
      // sum / sum-of-squares over lanes 0..31 (same add order as before)
      float sv = (lane < NTOP) ? v : 0.0f;
      sv += fswap32(sv);
      sv += fswap16(sv);
      sv += fswap8(sv);
      sv += fswap4(sv);
      sv = DPPADD(sv, 0x4E);
      sv = DPPADD(sv, 0xB1);
      float mun = sv / 32.0f;
      float dv = (lane < NTOP) ? (v - mun) : 0.0f;
      float s2 = dv*dv;
      s2 += fswap32(s2);
      s2 += fswap16(s2);
      s2 += fswap8(s2);
      s2 += fswap4(s2);
      s2 = DPPADD(s2, 0x4E);
      s2 = DPPADD(s2, 0xB1);
      float stdv = sqrtf(s2 / 31.0f);
      if (t == 98){
        if (lane == 0) out[b] = mun * 6.2831854820251465f;  // fp32(2*pi)
      } else if (lane < MCAND){
        float e = EPSG ? epsv : EPB[lane];
        A[lane] = fmaf(stdv, e, mun);                       // a(t+1)
      }
    }
    __syncthreads();   // B2: a(t+1) visible; QB/EPB free for reuse
  }
}

extern "C" void kernel_launch(void* const* d_in, const int* in_sizes, int n_in,
                              void* d_out, int out_size, void* d_ws, size_t ws_size,
                              hipStream_t stream) {
  const float* states = (const float*)d_in[0];
  const float* W1     = (const float*)d_in[1];
  const float* b1     = (const float*)d_in[2];
  const float* W2     = (const float*)d_in[3];
  const float* b2     = (const float*)d_in[4];
  const float* W3     = (const float*)d_in[5];
  const float* b3     = (const float*)d_in[6];
  float* out = (float*)d_out;

  if (d_ws != nullptr && ws_size >= WS_NEED){
    uint32_t* K = (uint32_t*)d_ws;
    float*    E = (float*)((char*)d_ws + 1024);
    hipLaunchKernelGGL(keys_kernel, dim3(1), dim3(128), 0, stream, K);
    hipLaunchKernelGGL(eps_kernel, dim3(EPS_ELEMS/256), dim3(256), 0, stream, K, E);
    hipLaunchKernelGGL(HIP_KERNEL_NAME(cem_kernel<true>), dim3(BATCH), dim3(512), 0, stream,
                       states, W1, b1, W2, b2, W3, b3, (const float*)E, out);
  } else {
    hipLaunchKernelGGL(HIP_KERNEL_NAME(cem_kernel<false>), dim3(BATCH), dim3(512), 0, stream,
                       states, W1, b1, W2, b2, W3, b3, (const float*)nullptr, out);
  }
}